// Round 1
// baseline (31.758 us; speedup 1.0000x reference)
//
#include <hip/hip_runtime.h>
#include <math.h>

// Problem constants (from reference)
#define Bn 256
#define Ln 2048
#define Dn 8
#define NPn 36
#define EPSd 1e-4
#define DIAG_MIN 0.1

__device__ __forceinline__ double silu_d(double x) { return x / (1.0 + exp(-x)); }
__device__ __forceinline__ double softplus_d(double x) {
    return fmax(x, 0.0) + log1p(exp(-fabs(x)));
}

// One block per batch row, 64 threads.
__global__ __launch_bounds__(64) void memodel_kernel(
    const float* __restrict__ values,
    const float* __restrict__ se_in_w, const float* __restrict__ se_in_b,
    const float* __restrict__ se_conv_w, const float* __restrict__ se_conv_b,
    const float* __restrict__ se_out_w, const float* __restrict__ se_out_b,
    const float* __restrict__ me_w1, const float* __restrict__ me_b1,
    const float* __restrict__ me_w2, const float* __restrict__ me_b2,
    const float* __restrict__ ef_w1, const float* __restrict__ ef_b1,
    const float* __restrict__ ef_w2, const float* __restrict__ ef_b2,
    const float* __restrict__ ef_scale,
    const float* __restrict__ mu_w1, const float* __restrict__ mu_b1,
    const float* __restrict__ mu_w2, const float* __restrict__ mu_b2,
    float* __restrict__ out)
{
    const int b = blockIdx.x;
    const int tid = threadIdx.x;

    // LDS
    __shared__ double w_me1[16 * 8], b_me1[16], w_me2[36 * 16], b_me2[36];
    __shared__ double h16[4][16];   // in-proj at t = L-4..L-1
    __shared__ double sh[2][8];     // silu(conv) at t = L-2, L-1
    __shared__ double zl[2][8];     // z at t = L-2, L-1
    __shared__ double Lm_s[36];     // Cholesky factor at z_last
    __shared__ double g_s[17][36];  // metric matrices (sym storage), slots 1..16 used
    __shared__ double Apart[8][8];
    __shared__ double Bpart[8];

    // Preload metric-net weights (used 17x per block)
    for (int i = tid; i < 128; i += 64) w_me1[i] = (double)me_w1[i];
    for (int i = tid; i < 16;  i += 64) b_me1[i] = (double)me_b1[i];
    for (int i = tid; i < 576; i += 64) w_me2[i] = (double)me_w2[i];
    for (int i = tid; i < 36;  i += 64) b_me2[i] = (double)me_b2[i];

    // Phase 1a: in-projection h = v * se_in_w + se_in_b at 4 trailing steps.
    {
        int t = tid >> 4, c = tid & 15;  // 64 threads = 4 t x 16 c
        double v = (double)values[(size_t)b * Ln + (Ln - 4 + t)];
        h16[t][c] = (double)se_in_w[c] * v + (double)se_in_b[c];
    }
    __syncthreads();

    // Phase 1b: causal conv (kernel 3, left-pad 2) + silu, at t = L-2, L-1.
    if (tid < 16) {
        int t = tid >> 3, d = tid & 7;   // t=0 -> L-2, t=1 -> L-1
        double s = (double)se_conv_b[d];
        for (int k = 0; k < 3; ++k)
            for (int c = 0; c < 16; ++c)
                s += (double)se_conv_w[d * 48 + c * 3 + k] * h16[t + k][c];
        sh[t][d] = silu_d(s);
    }
    __syncthreads();

    // Phase 1c: out-projection -> z at t = L-2, L-1.
    if (tid < 16) {
        int t = tid >> 3, d = tid & 7;
        double s = (double)se_out_b[d];
        for (int c = 0; c < 8; ++c) s += (double)se_out_w[d * 8 + c] * sh[t][c];
        zl[t][d] = s;
    }
    __syncthreads();

    // Phase 2: 17 metric evaluations.
    // tid==0: base (keep Cholesky factor Lm). tid 1..8: +eps e_{tid-1}. tid 9..16: -eps e_{tid-9}.
    if (tid < 17) {
        double zz[8];
        for (int i = 0; i < 8; ++i) zz[i] = zl[1][i];
        if (tid > 0) {
            int r = (tid - 1) & 7;
            zz[r] += (tid <= 8) ? EPSd : -EPSd;
        }
        double h1[16];
        for (int j = 0; j < 16; ++j) {
            double s = b_me1[j];
            for (int i = 0; i < 8; ++i) s += w_me1[j * 8 + i] * zz[i];
            h1[j] = silu_d(s);
        }
        double Lr[36];
        for (int m = 0; m < 36; ++m) {
            double s = b_me2[m];
            for (int j = 0; j < 16; ++j) s += w_me2[m * 16 + j] * h1[j];
            Lr[m] = s;
        }
        // diag entries (tril row-major): m = r(r+1)/2 + r -> softplus + DIAG_MIN
        for (int r = 0; r < 8; ++r) {
            int m = r * (r + 1) / 2 + r;
            Lr[m] = softplus_d(Lr[m]) + DIAG_MIN;
        }
        if (tid == 0) {
            for (int m = 0; m < 36; ++m) Lm_s[m] = Lr[m];
        } else {
            // g = Lm Lm^T, symmetric storage g[i][j], i>=j at index i(i+1)/2+j
            for (int i = 0; i < 8; ++i) {
                int ti = i * (i + 1) / 2;
                for (int j = 0; j <= i; ++j) {
                    int tj = j * (j + 1) / 2;
                    double s = 0.0;
                    for (int k = 0; k <= j; ++k) s += Lr[ti + k] * Lr[tj + k];
                    g_s[tid][ti + j] = s;
                }
            }
        }
    }
    __syncthreads();

    // Phase 3: per-direction FD contraction.
    // Dg_r = (g(+r) - g(-r)) / (2 eps);  w = Dg_r dz;  A += dz_r * w;  B_r = dz . w
    if (tid < 8) {
        const int r = tid;
        double dz[8];
        for (int i = 0; i < 8; ++i) dz[i] = zl[1][i] - zl[0][i];
        double Dg[8][8];
        const double inv2e = 1.0 / (2.0 * EPSd);
        for (int i = 0; i < 8; ++i)
            for (int j = 0; j <= i; ++j) {
                int m = i * (i + 1) / 2 + j;
                double d = (g_s[1 + r][m] - g_s[9 + r][m]) * inv2e;
                Dg[i][j] = d; Dg[j][i] = d;
            }
        double w[8]; double Br = 0.0;
        for (int l = 0; l < 8; ++l) {
            double s = 0.0;
            for (int i = 0; i < 8; ++i) s += Dg[i][l] * dz[i];
            w[l] = s;
            Br += s * dz[l];
        }
        for (int l = 0; l < 8; ++l) Apart[r][l] = dz[r] * w[l];
        Bpart[r] = Br;
    }
    __syncthreads();

    // Phase 4: combine, solve, heads, output. Single thread (tiny).
    if (tid == 0) {
        double v[8];
        for (int l = 0; l < 8; ++l) {
            double a = 0.0;
            for (int r = 0; r < 8; ++r) a += Apart[r][l];
            v[l] = 2.0 * a - Bpart[l];
        }
        // Solve g x = v via Cholesky factor Lm (g = Lm Lm^T).
        double y[8];
        for (int i = 0; i < 8; ++i) {
            double s = v[i];
            for (int j = 0; j < i; ++j) s -= Lm_s[i * (i + 1) / 2 + j] * y[j];
            y[i] = s / Lm_s[i * (i + 1) / 2 + i];
        }
        double x[8];
        for (int i = 7; i >= 0; --i) {
            double s = y[i];
            for (int j = i + 1; j < 8; ++j) s -= Lm_s[j * (j + 1) / 2 + i] * x[j];
            x[i] = s / Lm_s[i * (i + 1) / 2 + i];
        }
        double ageo[8];
        for (int i = 0; i < 8; ++i) ageo[i] = -0.5 * x[i];

        // External-force head: f_in = [z_last, dz]
        double fin[16];
        for (int i = 0; i < 8; ++i) {
            fin[i] = zl[1][i];
            fin[8 + i] = zl[1][i] - zl[0][i];
        }
        double h2[16];
        for (int j = 0; j < 16; ++j) {
            double s = (double)ef_b1[j];
            for (int i = 0; i < 16; ++i) s += (double)ef_w1[j * 16 + i] * fin[i];
            h2[j] = tanh(s);
        }
        double scale = (double)ef_scale[0];
        double d2z[8];
        for (int dd = 0; dd < 8; ++dd) {
            double s = (double)ef_b2[dd];
            for (int j = 0; j < 16; ++j) s += (double)ef_w2[dd * 16 + j] * h2[j];
            d2z[dd] = ageo[dd] + s * scale;
        }
        // mu head
        double h3[8];
        for (int j = 0; j < 8; ++j) {
            double s = (double)mu_b1[j];
            for (int i = 0; i < 8; ++i) s += (double)mu_w1[j * 8 + i] * d2z[i];
            h3[j] = silu_d(s);
        }
        double mu = (double)mu_b2[0];
        for (int j = 0; j < 8; ++j) mu += (double)mu_w2[j] * h3[j];

        double vL1 = (double)values[(size_t)b * Ln + (Ln - 1)];
        double vL2 = (double)values[(size_t)b * Ln + (Ln - 2)];
        out[b] = (float)(vL1 + (vL1 - vL2) + mu);
    }
}

extern "C" void kernel_launch(void* const* d_in, const int* in_sizes, int n_in,
                              void* d_out, int out_size, void* d_ws, size_t ws_size,
                              hipStream_t stream) {
    (void)in_sizes; (void)n_in; (void)out_size; (void)d_ws; (void)ws_size;
    const float* values    = (const float*)d_in[0];
    const float* se_in_w   = (const float*)d_in[1];
    const float* se_in_b   = (const float*)d_in[2];
    const float* se_conv_w = (const float*)d_in[3];
    const float* se_conv_b = (const float*)d_in[4];
    const float* se_out_w  = (const float*)d_in[5];
    const float* se_out_b  = (const float*)d_in[6];
    const float* me_w1     = (const float*)d_in[7];
    const float* me_b1     = (const float*)d_in[8];
    const float* me_w2     = (const float*)d_in[9];
    const float* me_b2     = (const float*)d_in[10];
    const float* ef_w1     = (const float*)d_in[11];
    const float* ef_b1     = (const float*)d_in[12];
    const float* ef_w2     = (const float*)d_in[13];
    const float* ef_b2     = (const float*)d_in[14];
    const float* ef_scale  = (const float*)d_in[15];
    const float* mu_w1     = (const float*)d_in[16];
    const float* mu_b1     = (const float*)d_in[17];
    const float* mu_w2     = (const float*)d_in[18];
    const float* mu_b2     = (const float*)d_in[19];
    float* out = (float*)d_out;

    hipLaunchKernelGGL(memodel_kernel, dim3(Bn), dim3(64), 0, stream,
                       values, se_in_w, se_in_b, se_conv_w, se_conv_b,
                       se_out_w, se_out_b, me_w1, me_b1, me_w2, me_b2,
                       ef_w1, ef_b1, ef_w2, ef_b2, ef_scale,
                       mu_w1, mu_b1, mu_w2, mu_b2, out);
}

// Round 2
// 23.707 us; speedup vs baseline: 1.3396x; 1.3396x over previous
//
#include <hip/hip_runtime.h>
#include <math.h>

// Problem constants (from reference)
#define Bn 256
#define Ln 2048
#define EPSd 1e-4
#define DIAG_MIN 0.1

__device__ __forceinline__ double silu_d(double x) { return x / (1.0 + exp(-x)); }
__device__ __forceinline__ double softplus_d(double x) {
    return fmax(x, 0.0) + log1p(exp(-fabs(x)));
}

// tril row-major (i,j) for m = 0..35
__device__ const signed char ROW36[36] = {0,1,1,2,2,2,3,3,3,3,4,4,4,4,4,5,5,5,5,5,5,6,6,6,6,6,6,6,7,7,7,7,7,7,7,7};
__device__ const signed char COL36[36] = {0,0,1,0,1,2,0,1,2,3,0,1,2,3,4,0,1,2,3,4,5,0,1,2,3,4,5,6,0,1,2,3,4,5,6,7};
// diagonal m positions: 0,2,5,9,14,20,27,35
#define DIAG_MASK ((1ull<<0)|(1ull<<2)|(1ull<<5)|(1ull<<9)|(1ull<<14)|(1ull<<20)|(1ull<<27)|(1ull<<35))

// One block per batch row, 64 threads.
__global__ __launch_bounds__(64) void memodel_kernel(
    const float* __restrict__ values,
    const float* __restrict__ se_in_w, const float* __restrict__ se_in_b,
    const float* __restrict__ se_conv_w, const float* __restrict__ se_conv_b,
    const float* __restrict__ se_out_w, const float* __restrict__ se_out_b,
    const float* __restrict__ me_w1, const float* __restrict__ me_b1,
    const float* __restrict__ me_w2, const float* __restrict__ me_b2,
    const float* __restrict__ ef_w1, const float* __restrict__ ef_b1,
    const float* __restrict__ ef_w2, const float* __restrict__ ef_b2,
    const float* __restrict__ ef_scale,
    const float* __restrict__ mu_w1, const float* __restrict__ mu_b1,
    const float* __restrict__ mu_w2, const float* __restrict__ mu_b2,
    float* __restrict__ out)
{
    const int b = blockIdx.x;
    const int tid = threadIdx.x;

    __shared__ double w_me1[16 * 8], b_me1[16], w_me2[36 * 16], b_me2[36];
    __shared__ double h16[4][16];    // in-proj at t = L-4..L-1
    __shared__ double sh[2][8];      // silu(conv) at t = L-2, L-1
    __shared__ double zl[2][8];      // z at t = L-2, L-1
    __shared__ double zs[17][8];     // 17 metric-eval points
    __shared__ double h1s[17][16];   // hidden activations
    __shared__ double Lrs[17][36];   // tril factors (softplus'd diag)
    __shared__ double gs[17][36];    // g = L L^T (sym storage), slots 1..16
    __shared__ double Apart[8][8];
    __shared__ double Bpart[8];
    __shared__ double invdiag[8];
    __shared__ double solveV[8];
    __shared__ double ageo_s[8];
    __shared__ double h2s[16];
    __shared__ double d2z_s[8];
    __shared__ double h3s[8];

    // Preload metric-net weights as f64 (reused 17x)
    for (int i = tid; i < 128; i += 64) w_me1[i] = (double)me_w1[i];
    for (int i = tid; i < 16;  i += 64) b_me1[i] = (double)me_b1[i];
    for (int i = tid; i < 576; i += 64) w_me2[i] = (double)me_w2[i];
    for (int i = tid; i < 36;  i += 64) b_me2[i] = (double)me_b2[i];

    // Phase 1a: h = v * se_in_w + se_in_b at the 4 trailing steps (64 lanes).
    {
        int t = tid >> 4, c = tid & 15;
        double v = (double)values[(size_t)b * Ln + (Ln - 4 + t)];
        h16[t][c] = (double)se_in_w[c] * v + (double)se_in_b[c];
    }
    __syncthreads();

    // Phase 1b: causal conv (k=3, left-pad 2) + silu at t = L-2, L-1 (16 lanes).
    if (tid < 16) {
        int t = tid >> 3, d = tid & 7;
        double s = (double)se_conv_b[d];
        for (int k = 0; k < 3; ++k)
            for (int c = 0; c < 16; ++c)
                s += (double)se_conv_w[d * 48 + c * 3 + k] * h16[t + k][c];
        sh[t][d] = silu_d(s);
    }
    __syncthreads();

    // Phase 1c: out-projection -> z (16 lanes).
    if (tid < 16) {
        int t = tid >> 3, d = tid & 7;
        double s = (double)se_out_b[d];
        for (int c = 0; c < 8; ++c) s += (double)se_out_w[d * 8 + c] * sh[t][c];
        zl[t][d] = s;
    }
    __syncthreads();

    // Phase 2a: build the 17 eval points (e=0 base; 1..8 +eps; 9..16 -eps).
    for (int idx = tid; idx < 136; idx += 64) {
        int e = idx >> 3, i = idx & 7;
        double v = zl[1][i];
        if (e >= 1 && e <= 8)  { if (i == e - 1) v += EPSd; }
        else if (e >= 9)       { if (i == e - 9) v -= EPSd; }
        zs[e][i] = v;
    }
    __syncthreads();

    // Phase 2b: h1 = silu(me_w1 zz + b1): 17*16 = 272 dot-8s over 64 lanes.
    for (int idx = tid; idx < 272; idx += 64) {
        int e = idx >> 4, j = idx & 15;
        double s = b_me1[j];
        const double* w = &w_me1[j * 8];
        const double* z = &zs[e][0];
        for (int i = 0; i < 8; ++i) s += w[i] * z[i];
        h1s[e][j] = silu_d(s);
    }
    __syncthreads();

    // Phase 2c: Lr = me_w2 h1 + b2 (+softplus on diag): 17*36 = 612 dot-16s.
    for (int idx = tid; idx < 612; idx += 64) {
        int e = idx / 36, m = idx - e * 36;
        double s = b_me2[m];
        const double* w = &w_me2[m * 16];
        const double* h = &h1s[e][0];
        for (int j = 0; j < 16; ++j) s += w[j] * h[j];
        if ((DIAG_MASK >> m) & 1ull) s = softplus_d(s) + DIAG_MIN;
        Lrs[e][m] = s;
    }
    __syncthreads();

    // Phase 2d: g = L L^T for e = 1..16: 576 short dots.
    for (int idx = tid; idx < 576; idx += 64) {
        int e = 1 + idx / 36, m = idx - (e - 1) * 36;
        int i = ROW36[m], j = COL36[m];
        const double* Li = &Lrs[e][i * (i + 1) / 2];
        const double* Lj = &Lrs[e][j * (j + 1) / 2];
        double s = 0.0;
        for (int k = 0; k <= j; ++k) s += Li[k] * Lj[k];
        gs[e][m] = s;
    }
    __syncthreads();

    // Phase 3: FD contraction (lanes 0..7) + diag reciprocals (lanes 8..15).
    if (tid >= 8 && tid < 16) {
        int i = tid - 8;
        invdiag[i] = 1.0 / Lrs[0][i * (i + 1) / 2 + i];
    }
    if (tid < 8) {
        const int r = tid;
        double dz[8];
        for (int i = 0; i < 8; ++i) dz[i] = zl[1][i] - zl[0][i];
        double Dg[8][8];
        const double inv2e = 1.0 / (2.0 * EPSd);
        for (int m = 0; m < 36; ++m) {
            int i = ROW36[m], j = COL36[m];
            double d = (gs[1 + r][m] - gs[9 + r][m]) * inv2e;
            Dg[i][j] = d; Dg[j][i] = d;
        }
        double w[8]; double Br = 0.0;
        for (int l = 0; l < 8; ++l) {
            double s = 0.0;
            for (int i = 0; i < 8; ++i) s += Dg[i][l] * dz[i];
            w[l] = s;
            Br += s * dz[l];
        }
        for (int l = 0; l < 8; ++l) Apart[r][l] = dz[r] * w[l];
        Bpart[r] = Br;
    }
    __syncthreads();

    // Phase 4a: v[l] = 2*sum_r A[r][l] - B[l]  (8 lanes).
    if (tid < 8) {
        double a = 0.0;
        for (int r = 0; r < 8; ++r) a += Apart[r][tid];
        solveV[tid] = 2.0 * a - Bpart[tid];
    }
    __syncthreads();

    // Phase 4b: solve g x = v via the Cholesky factor (serial, lane 0).
    if (tid == 0) {
        double y[8];
        for (int i = 0; i < 8; ++i) {
            double s = solveV[i];
            const double* Li = &Lrs[0][i * (i + 1) / 2];
            for (int j = 0; j < i; ++j) s -= Li[j] * y[j];
            y[i] = s * invdiag[i];
        }
        double x[8];
        for (int i = 7; i >= 0; --i) {
            double s = y[i];
            for (int j = i + 1; j < 8; ++j) s -= Lrs[0][j * (j + 1) / 2 + i] * x[j];
            x[i] = s * invdiag[i];
            ageo_s[i] = -0.5 * x[i];
        }
    }
    __syncthreads();

    // Phase 4c: ef head layer 1 (16 lanes): h2 = tanh(ef_w1 [z,dz] + b1).
    if (tid < 16) {
        double s = (double)ef_b1[tid];
        const float* w = &ef_w1[tid * 16];
        for (int i = 0; i < 8; ++i)  s += (double)w[i] * zl[1][i];
        for (int i = 0; i < 8; ++i)  s += (double)w[8 + i] * (zl[1][i] - zl[0][i]);
        h2s[tid] = tanh(s);
    }
    __syncthreads();

    // Phase 4d: d2z = a_geo + ef_scale * (ef_w2 h2 + b2)  (8 lanes).
    if (tid < 8) {
        double s = (double)ef_b2[tid];
        const float* w = &ef_w2[tid * 16];
        for (int j = 0; j < 16; ++j) s += (double)w[j] * h2s[j];
        d2z_s[tid] = ageo_s[tid] + s * (double)ef_scale[0];
    }
    __syncthreads();

    // Phase 4e: mu head layer 1 (8 lanes): h3 = silu(mu_w1 d2z + b1).
    if (tid < 8) {
        double s = (double)mu_b1[tid];
        const float* w = &mu_w1[tid * 8];
        for (int i = 0; i < 8; ++i) s += (double)w[i] * d2z_s[i];
        h3s[tid] = silu_d(s);
    }
    __syncthreads();

    // Phase 4f: final dot + output (lane 0).
    if (tid == 0) {
        double mu = (double)mu_b2[0];
        for (int j = 0; j < 8; ++j) mu += (double)mu_w2[j] * h3s[j];
        double vL1 = (double)values[(size_t)b * Ln + (Ln - 1)];
        double vL2 = (double)values[(size_t)b * Ln + (Ln - 2)];
        out[b] = (float)(vL1 + (vL1 - vL2) + mu);
    }
}

extern "C" void kernel_launch(void* const* d_in, const int* in_sizes, int n_in,
                              void* d_out, int out_size, void* d_ws, size_t ws_size,
                              hipStream_t stream) {
    (void)in_sizes; (void)n_in; (void)out_size; (void)d_ws; (void)ws_size;
    const float* values    = (const float*)d_in[0];
    const float* se_in_w   = (const float*)d_in[1];
    const float* se_in_b   = (const float*)d_in[2];
    const float* se_conv_w = (const float*)d_in[3];
    const float* se_conv_b = (const float*)d_in[4];
    const float* se_out_w  = (const float*)d_in[5];
    const float* se_out_b  = (const float*)d_in[6];
    const float* me_w1     = (const float*)d_in[7];
    const float* me_b1     = (const float*)d_in[8];
    const float* me_w2     = (const float*)d_in[9];
    const float* me_b2     = (const float*)d_in[10];
    const float* ef_w1     = (const float*)d_in[11];
    const float* ef_b1     = (const float*)d_in[12];
    const float* ef_w2     = (const float*)d_in[13];
    const float* ef_b2     = (const float*)d_in[14];
    const float* ef_scale  = (const float*)d_in[15];
    const float* mu_w1     = (const float*)d_in[16];
    const float* mu_b1     = (const float*)d_in[17];
    const float* mu_w2     = (const float*)d_in[18];
    const float* mu_b2     = (const float*)d_in[19];
    float* out = (float*)d_out;

    hipLaunchKernelGGL(memodel_kernel, dim3(Bn), dim3(64), 0, stream,
                       values, se_in_w, se_in_b, se_conv_w, se_conv_b,
                       se_out_w, se_out_b, me_w1, me_b1, me_w2, me_b2,
                       ef_w1, ef_b1, ef_w2, ef_b2, ef_scale,
                       mu_w1, mu_b1, mu_w2, mu_b2, out);
}

// Round 3
// 15.932 us; speedup vs baseline: 1.9934x; 1.4880x over previous
//
#include <hip/hip_runtime.h>
#include <math.h>

// Problem constants (from reference)
#define Bn 256
#define Ln 2048
#define EPSd 1e-4
#define DIAG_MIN 0.1

#define W2PAD 17  // pad w_me2 rows (16 -> 17 doubles) to break LDS bank aliasing

__device__ __forceinline__ double silu_d(double x) { return x / (1.0 + exp(-x)); }
__device__ __forceinline__ double softplus_d(double x) {
    return fmax(x, 0.0) + log1p(exp(-fabs(x)));
}

// tril row-major (i,j) for m = 0..35
__device__ const signed char ROW36[36] = {0,1,1,2,2,2,3,3,3,3,4,4,4,4,4,5,5,5,5,5,5,6,6,6,6,6,6,6,7,7,7,7,7,7,7,7};
__device__ const signed char COL36[36] = {0,0,1,0,1,2,0,1,2,3,0,1,2,3,4,0,1,2,3,4,5,0,1,2,3,4,5,6,0,1,2,3,4,5,6,7};
// diagonal m positions: 0,2,5,9,14,20,27,35
#define DIAG_MASK ((1ull<<0)|(1ull<<2)|(1ull<<5)|(1ull<<9)|(1ull<<14)|(1ull<<20)|(1ull<<27)|(1ull<<35))

// One block per batch row, 256 threads (4 waves).
__global__ __launch_bounds__(256) void memodel_kernel(
    const float* __restrict__ values,
    const float* __restrict__ se_in_w, const float* __restrict__ se_in_b,
    const float* __restrict__ se_conv_w, const float* __restrict__ se_conv_b,
    const float* __restrict__ se_out_w, const float* __restrict__ se_out_b,
    const float* __restrict__ me_w1, const float* __restrict__ me_b1,
    const float* __restrict__ me_w2, const float* __restrict__ me_b2,
    const float* __restrict__ ef_w1, const float* __restrict__ ef_b1,
    const float* __restrict__ ef_w2, const float* __restrict__ ef_b2,
    const float* __restrict__ ef_scale,
    const float* __restrict__ mu_w1, const float* __restrict__ mu_b1,
    const float* __restrict__ mu_w2, const float* __restrict__ mu_b2,
    float* __restrict__ out)
{
    const int b = blockIdx.x;
    const int tid = threadIdx.x;

    __shared__ double w_me1[16 * 8], b_me1[16], w_me2[36 * W2PAD], b_me2[36];
    __shared__ double h16[4][16];    // in-proj at t = L-4..L-1
    __shared__ double sh[2][8];      // silu(conv) at t = L-2, L-1
    __shared__ double zl[2][8];      // z at t = L-2, L-1
    __shared__ double zs[17][8];     // 17 metric-eval points
    __shared__ double h1s[17][16];   // hidden activations
    __shared__ double Lrs[17][36];   // tril factors (softplus'd diag)
    __shared__ double gs[17][36];    // g = L L^T (sym storage), slots 1..16
    __shared__ double Apart[8][8];
    __shared__ double Bpart[8];
    __shared__ double invdiag[8];
    __shared__ double solveV[8];
    __shared__ double ageo_s[8];
    __shared__ double h2s[16];
    __shared__ double d2z_s[8];
    __shared__ double h3s[8];

    // Preload metric-net weights as f64 (reused 17x). 256 lanes: <=3 each.
    for (int i = tid; i < 128; i += 256) w_me1[i] = (double)me_w1[i];
    for (int i = tid; i < 16;  i += 256) b_me1[i] = (double)me_b1[i];
    for (int i = tid; i < 576; i += 256) {
        int m = i >> 4, j = i & 15;
        w_me2[m * W2PAD + j] = (double)me_w2[i];
    }
    for (int i = tid; i < 36;  i += 256) b_me2[i] = (double)me_b2[i];

    // Phase 1a: h = v * se_in_w + se_in_b at the 4 trailing steps (64 lanes).
    if (tid < 64) {
        int t = tid >> 4, c = tid & 15;
        double v = (double)values[(size_t)b * Ln + (Ln - 4 + t)];
        h16[t][c] = (double)se_in_w[c] * v + (double)se_in_b[c];
    }
    __syncthreads();

    // Phase 1b: causal conv (k=3, left-pad 2) + silu at t = L-2, L-1 (16 lanes).
    if (tid < 16) {
        int t = tid >> 3, d = tid & 7;
        double s = (double)se_conv_b[d];
        for (int k = 0; k < 3; ++k)
            for (int c = 0; c < 16; ++c)
                s += (double)se_conv_w[d * 48 + c * 3 + k] * h16[t + k][c];
        sh[t][d] = silu_d(s);
    }
    __syncthreads();

    // Phase 1c: out-projection -> z (16 lanes).
    if (tid < 16) {
        int t = tid >> 3, d = tid & 7;
        double s = (double)se_out_b[d];
        for (int c = 0; c < 8; ++c) s += (double)se_out_w[d * 8 + c] * sh[t][c];
        zl[t][d] = s;
    }
    __syncthreads();

    // Phase 2a: build the 17 eval points (e=0 base; 1..8 +eps; 9..16 -eps). 136 tasks.
    if (tid < 136) {
        int e = tid >> 3, i = tid & 7;
        double v = zl[1][i];
        if (e >= 1 && e <= 8)  { if (i == e - 1) v += EPSd; }
        else if (e >= 9)       { if (i == e - 9) v -= EPSd; }
        zs[e][i] = v;
    }
    __syncthreads();

    // Phase 2b: h1 = silu(me_w1 zz + b1): 272 dot-8s over 256 lanes.
    for (int idx = tid; idx < 272; idx += 256) {
        int e = idx >> 4, j = idx & 15;
        double s = b_me1[j];
        const double* w = &w_me1[j * 8];
        const double* z = &zs[e][0];
        for (int i = 0; i < 8; ++i) s += w[i] * z[i];
        h1s[e][j] = silu_d(s);
    }
    __syncthreads();

    // Phase 2c: Lr = me_w2 h1 + b2 (+softplus on diag): 612 dot-16s over 256 lanes.
    for (int idx = tid; idx < 612; idx += 256) {
        int e = idx / 36, m = idx - e * 36;
        double s = b_me2[m];
        const double* w = &w_me2[m * W2PAD];
        const double* h = &h1s[e][0];
        for (int j = 0; j < 16; ++j) s += w[j] * h[j];
        if ((DIAG_MASK >> m) & 1ull) s = softplus_d(s) + DIAG_MIN;
        Lrs[e][m] = s;
    }
    __syncthreads();

    // Phase 2d: g = L L^T for e = 1..16: 576 short dots over 256 lanes.
    for (int idx = tid; idx < 576; idx += 256) {
        int e = 1 + idx / 36, m = idx - (e - 1) * 36;
        int i = ROW36[m], j = COL36[m];
        const double* Li = &Lrs[e][i * (i + 1) / 2];
        const double* Lj = &Lrs[e][j * (j + 1) / 2];
        double s = 0.0;
        for (int k = 0; k <= j; ++k) s += Li[k] * Lj[k];
        gs[e][m] = s;
    }
    __syncthreads();

    // Phase 3: FD contraction (lanes 0..7) + diag reciprocals (lanes 8..15).
    if (tid >= 8 && tid < 16) {
        int i = tid - 8;
        invdiag[i] = 1.0 / Lrs[0][i * (i + 1) / 2 + i];
    }
    if (tid < 8) {
        const int r = tid;
        double dz[8];
        for (int i = 0; i < 8; ++i) dz[i] = zl[1][i] - zl[0][i];
        double Dg[8][8];
        const double inv2e = 1.0 / (2.0 * EPSd);
        for (int m = 0; m < 36; ++m) {
            int i = ROW36[m], j = COL36[m];
            double d = (gs[1 + r][m] - gs[9 + r][m]) * inv2e;
            Dg[i][j] = d; Dg[j][i] = d;
        }
        double w[8]; double Br = 0.0;
        for (int l = 0; l < 8; ++l) {
            double s = 0.0;
            for (int i = 0; i < 8; ++i) s += Dg[i][l] * dz[i];
            w[l] = s;
            Br += s * dz[l];
        }
        for (int l = 0; l < 8; ++l) Apart[r][l] = dz[r] * w[l];
        Bpart[r] = Br;
    }
    __syncthreads();

    // Phase 4a: v[l] = 2*sum_r A[r][l] - B[l]  (8 lanes).
    if (tid < 8) {
        double a = 0.0;
        for (int r = 0; r < 8; ++r) a += Apart[r][tid];
        solveV[tid] = 2.0 * a - Bpart[tid];
    }
    __syncthreads();

    // Phase 4b: solve g x = v via the Cholesky factor (serial, lane 0).
    if (tid == 0) {
        double y[8];
        for (int i = 0; i < 8; ++i) {
            double s = solveV[i];
            const double* Li = &Lrs[0][i * (i + 1) / 2];
            for (int j = 0; j < i; ++j) s -= Li[j] * y[j];
            y[i] = s * invdiag[i];
        }
        double x[8];
        for (int i = 7; i >= 0; --i) {
            double s = y[i];
            for (int j = i + 1; j < 8; ++j) s -= Lrs[0][j * (j + 1) / 2 + i] * x[j];
            x[i] = s * invdiag[i];
            ageo_s[i] = -0.5 * x[i];
        }
    }
    __syncthreads();

    // Phase 4c: ef head layer 1 (16 lanes): h2 = tanh(ef_w1 [z,dz] + b1).
    if (tid < 16) {
        double s = (double)ef_b1[tid];
        const float* w = &ef_w1[tid * 16];
        for (int i = 0; i < 8; ++i)  s += (double)w[i] * zl[1][i];
        for (int i = 0; i < 8; ++i)  s += (double)w[8 + i] * (zl[1][i] - zl[0][i]);
        h2s[tid] = tanh(s);
    }
    __syncthreads();

    // Phase 4d: d2z = a_geo + ef_scale * (ef_w2 h2 + b2)  (8 lanes).
    if (tid < 8) {
        double s = (double)ef_b2[tid];
        const float* w = &ef_w2[tid * 16];
        for (int j = 0; j < 16; ++j) s += (double)w[j] * h2s[j];
        d2z_s[tid] = ageo_s[tid] + s * (double)ef_scale[0];
    }
    __syncthreads();

    // Phase 4e: mu head layer 1 (8 lanes): h3 = silu(mu_w1 d2z + b1).
    if (tid < 8) {
        double s = (double)mu_b1[tid];
        const float* w = &mu_w1[tid * 8];
        for (int i = 0; i < 8; ++i) s += (double)w[i] * d2z_s[i];
        h3s[tid] = silu_d(s);
    }
    __syncthreads();

    // Phase 4f: final dot + output (lane 0).
    if (tid == 0) {
        double mu = (double)mu_b2[0];
        for (int j = 0; j < 8; ++j) mu += (double)mu_w2[j] * h3s[j];
        double vL1 = (double)values[(size_t)b * Ln + (Ln - 1)];
        double vL2 = (double)values[(size_t)b * Ln + (Ln - 2)];
        out[b] = (float)(vL1 + (vL1 - vL2) + mu);
    }
}

extern "C" void kernel_launch(void* const* d_in, const int* in_sizes, int n_in,
                              void* d_out, int out_size, void* d_ws, size_t ws_size,
                              hipStream_t stream) {
    (void)in_sizes; (void)n_in; (void)out_size; (void)d_ws; (void)ws_size;
    const float* values    = (const float*)d_in[0];
    const float* se_in_w   = (const float*)d_in[1];
    const float* se_in_b   = (const float*)d_in[2];
    const float* se_conv_w = (const float*)d_in[3];
    const float* se_conv_b = (const float*)d_in[4];
    const float* se_out_w  = (const float*)d_in[5];
    const float* se_out_b  = (const float*)d_in[6];
    const float* me_w1     = (const float*)d_in[7];
    const float* me_b1     = (const float*)d_in[8];
    const float* me_w2     = (const float*)d_in[9];
    const float* me_b2     = (const float*)d_in[10];
    const float* ef_w1     = (const float*)d_in[11];
    const float* ef_b1     = (const float*)d_in[12];
    const float* ef_w2     = (const float*)d_in[13];
    const float* ef_b2     = (const float*)d_in[14];
    const float* ef_scale  = (const float*)d_in[15];
    const float* mu_w1     = (const float*)d_in[16];
    const float* mu_b1     = (const float*)d_in[17];
    const float* mu_w2     = (const float*)d_in[18];
    const float* mu_b2     = (const float*)d_in[19];
    float* out = (float*)d_out;

    hipLaunchKernelGGL(memodel_kernel, dim3(Bn), dim3(256), 0, stream,
                       values, se_in_w, se_in_b, se_conv_w, se_conv_b,
                       se_out_w, se_out_b, me_w1, me_b1, me_w2, me_b2,
                       ef_w1, ef_b1, ef_w2, ef_b2, ef_scale,
                       mu_w1, mu_b1, mu_w2, mu_b2, out);
}